// Round 7
// baseline (479.505 us; speedup 1.0000x reference)
//
#include <hip/hip_runtime.h>
#include <hip/hip_bf16.h>

#define C   336
#define CR  84
#define BB  256
#define HW  196           // 14*14
#define NKC 11            // K chunks of 32 (K padded to 352)
#define NNF 21            // 336/16 N fragments
#define PBLK 1568         // pack grid: 1568 blocks x 2 waves, 32 rows each
#define LDSW 344          // pack LDS row stride in shorts
#define HBLK 98           // gemm blocks per N-half
#define GBLK (2*HBLK)     // 196 total, all co-resident (1/CU)
#define BLDS (11*NKC*512*2)  // 123904 B dynamic LDS (F=11 half)

typedef __attribute__((ext_vector_type(8))) short bf16x8;
typedef __attribute__((ext_vector_type(4))) float f32x4;

typedef __attribute__((address_space(3))) void       lds_vp;
typedef const __attribute__((address_space(1))) void gbl_vp;

__device__ __forceinline__ short f2bf(float f) {
    unsigned u = __builtin_bit_cast(unsigned, f);
    u += 0x7fffu + ((u >> 16) & 1u);   // round-to-nearest-even
    return (short)(u >> 16);
}

__device__ __forceinline__ void gload_lds16(const short* g, short* l) {
    __builtin_amdgcn_global_load_lds((gbl_vp*)g, (lds_vp*)l, 16, 0, 0);
}

// ---------------------------------------------------------------- prep w53 -> bf16 frag-linear (tight, 21 frags/kc)
// wbf[((kc*21+nf)*64 + lane)*8 + j] = bf16(w53[o][c]), o=nf*16+(lane&15), c=kc*32+(lane>>4)*8+j
__global__ void prep_w(const float* __restrict__ w53, short* __restrict__ wbf) {
    const int f = blockIdx.x;           // 0..230
    const int kc = f / NNF, nf = f - kc * NNF;
    const int lane = threadIdx.x;
    const int o = nf * 16 + (lane & 15);
    const int cb = kc * 32 + (lane >> 4) * 8;
    short* dst = wbf + ((size_t)f * 64 + lane) * 8;
#pragma unroll
    for (int j = 0; j < 8; ++j) {
        const int c = cb + j;
        dst[j] = (c < C) ? f2bf(w53[o * C + c]) : (short)0;
    }
}

// ---------------------------------------------------------------- SE gate: LDS-staged weights, 8 batches/block
__global__ __launch_bounds__(256) void gate_kernel(
    const float* __restrict__ x160,
    const float* __restrict__ w51, const float* __restrict__ b51,
    const float* __restrict__ w52, const float* __restrict__ b52,
    float* __restrict__ gate)
{
    __shared__ float sx[8 * C];        // 10752 B
    __shared__ float wv[8 * C];        // staged weight rows (reused both layers)
    __shared__ float hb[8 * CR];       // 2688 B
    const int t = threadIdx.x;
    const int b0 = blockIdx.x * 8;

    for (int i = t; i < 8 * C; i += 256) sx[i] = x160[b0 * C + i];
    __syncthreads();

    // layer 1: h[b][o] = relu(sum_c w51[o][c]*s[b][c] + b51[o]); chunks of 8 o-rows
    for (int o0 = 0; o0 < CR; o0 += 8) {
        const int nrows = (CR - o0 < 8) ? (CR - o0) : 8;
        for (int i = t; i < nrows * C; i += 256) wv[i] = w51[o0 * C + i];
        __syncthreads();
        const int pair = t >> 2, kq = t & 3;      // 64 pairs x 4-way k-split
        const int b = pair >> 3, r = pair & 7;
        float v = 0.f;
        if (r < nrows) {
            const float* wr = wv + r * C + kq * 84;
            const float* xr = sx + b * C + kq * 84;
            for (int c = 0; c < 84; ++c) v = fmaf(wr[c], xr[c], v);
        }
        v += __shfl_xor(v, 1);
        v += __shfl_xor(v, 2);
        if (kq == 0 && r < nrows)
            hb[b * CR + o0 + r] = fmaxf(v + b51[o0 + r], 0.f);
        __syncthreads();
    }

    // layer 2: gate[b][o] = sigmoid(sum_j w52[o][j]*h[b][j] + b52[o]); chunks of 32 o-rows
    for (int o0 = 0; o0 < C; o0 += 32) {
        const int nrows = (C - o0 < 32) ? (C - o0) : 32;
        for (int i = t; i < nrows * CR; i += 256) wv[i] = w52[o0 * CR + i];
        __syncthreads();
        const int b = t >> 5, r = t & 31;
        if (r < nrows) {
            const float* wr = wv + r * CR;
            const float* hr = hb + b * CR;
            float v = b52[o0 + r];
            for (int j = 0; j < CR; ++j) v = fmaf(wr[j], hr[j], v);
            gate[(b0 + b) * C + o0 + r] = 1.f / (1.f + expf(-v));
        }
        __syncthreads();
    }
}

// ---------------------------------------------------------------- pack A = bf16(x159*gate), frag-linear
__global__ __launch_bounds__(128) void pack_kernel(
    const float* __restrict__ x159, const float* __restrict__ gate,
    short* __restrict__ apack)
{
    __shared__ short at[32 * LDSW];    // 22016 B
    const int tid  = threadIdx.x;
    const int lane = tid & 63;
    const int wq   = tid >> 6;         // 0..1
    const int m0   = blockIdx.x * 32;

    {   // phase 1: 64 lanes = 32 consecutive m x 2 c (coalesced)
        const int ml = lane & 31;
        const int ch = lane >> 5;
        const int m = m0 + ml;
        const int b = m / HW;
        const int p = m - b * HW;
        const float* __restrict__ xb = x159 + (size_t)b * (C * HW) + p;
        const float* __restrict__ gb = gate + b * C;
        short* row = at + ml * LDSW;
        for (int c = wq * 2 + ch; c < C; c += 4)
            row[c] = f2bf(xb[(size_t)c * HW] * gb[c]);
        const int z = 336 + (wq * 2 + ch) * 2;    // zero pad cols 336..343
        row[z] = 0; row[z + 1] = 0;
    }
    __syncthreads();

    {   // phase 2: wave wq -> tile blk*2+wq, 1KB contiguous coalesced store per kc
        const int row = lane & 15;
        const int kg  = lane >> 4;
        const short* src = at + ((wq & 1) * 16 + row) * LDSW;
        short* dst = apack + ((size_t)(blockIdx.x * 2 + wq) * NKC * 64 + lane) * 8;
#pragma unroll
        for (int kc = 0; kc < NKC; ++kc) {
            const int c0 = kc * 32 + kg * 8;
            bf16x8 v = {0,0,0,0,0,0,0,0};
            if (c0 < LDSW) v = *(const bf16x8*)(src + c0);   // c0==344 -> zero frag
            *(bf16x8*)(dst + (size_t)kc * 512) = v;
        }
    }
}

// ---------------------------------------------------------------- persistent-B GEMM body
// F frags (FBASE..FBASE+F-1) resident in LDS; each wave free-runs 2 pair-jobs (4 m-tiles).
template<int F, int FBASE, bool STATS>
__device__ __forceinline__ void gemm_body(
    const short* __restrict__ apack, const short* __restrict__ wbf,
    const float* __restrict__ ab, float* __restrict__ outp,
    float* __restrict__ part, int bi, char* smem)
{
    short* bsm = (short*)smem;
    const int tid = threadIdx.x, lane = tid & 63, wid = tid >> 6;
    const int r = lane & 15, kg = lane >> 4;

    // load this half's entire B into LDS (once)
    for (int s = wid; s < F * NKC; s += 8) {
        const int kc = s / F, f = s - kc * F;
        gload_lds16(wbf + ((size_t)(kc * NNF + FBASE + f) * 64 + lane) * 8,
                    bsm + (size_t)s * 512);
    }

    float af[F], bfc[F], sf[F], qf[F];
#pragma unroll
    for (int f = 0; f < F; ++f) {
        if (STATS) { sf[f] = 0.f; qf[f] = 0.f; }
        else {
            const int o = (FBASE + f) * 16 + r;
            af[f] = ab[2 * o]; bfc[f] = ab[2 * o + 1];
        }
    }

    asm volatile("s_waitcnt vmcnt(0)" ::: "memory");
    __syncthreads();                   // B resident; no more barriers until epilogue

    const int g = bi * 8 + wid;        // 0..783: this wave's job id
    for (int pj = 0; pj < 2; ++pj) {
        const int t0 = g * 4 + pj * 2; // pair of tiles t0, t0+1
        const short* ap0 = apack + ((size_t)t0 * NKC * 64 + lane) * 8;
        const short* ap1 = ap0 + NKC * 512;
        f32x4 acc0[F], acc1[F];
#pragma unroll
        for (int f = 0; f < F; ++f) { acc0[f] = f32x4{0.f,0.f,0.f,0.f}; acc1[f] = f32x4{0.f,0.f,0.f,0.f}; }
        bf16x8 a0 = *(const bf16x8*)ap0;
        bf16x8 a1 = *(const bf16x8*)ap1;
        for (int kc = 0; kc < NKC; ++kc) {
            bf16x8 n0 = a0, n1 = a1;
            if (kc + 1 < NKC) {
                n0 = *(const bf16x8*)(ap0 + (size_t)(kc + 1) * 512);
                n1 = *(const bf16x8*)(ap1 + (size_t)(kc + 1) * 512);
            }
            const short* bb = bsm + (size_t)kc * F * 512 + lane * 8;
#pragma unroll
            for (int f = 0; f < F; ++f) {
                const bf16x8 bfrag = *(const bf16x8*)(bb + (size_t)f * 512);
                acc0[f] = __builtin_amdgcn_mfma_f32_16x16x32_bf16(a0, bfrag, acc0[f], 0, 0, 0);
                acc1[f] = __builtin_amdgcn_mfma_f32_16x16x32_bf16(a1, bfrag, acc1[f], 0, 0, 0);
            }
            a0 = n0; a1 = n1;
        }
        if (STATS) {
#pragma unroll
            for (int f = 0; f < F; ++f) {
#pragma unroll
                for (int j = 0; j < 4; ++j) {
                    sf[f] += acc0[f][j] + acc1[f][j];
                    qf[f] += acc0[f][j]*acc0[f][j] + acc1[f][j]*acc1[f][j];
                }
            }
        } else {
#pragma unroll
            for (int u = 0; u < 2; ++u) {
                const int mC = (t0 + u) * 16 + kg * 4;
                const int bC = mC / HW;
                const int pC = mC - bC * HW;
                float* __restrict__ ob = outp + (size_t)bC * (C * HW) + pC;
                const f32x4* A = u ? acc1 : acc0;
#pragma unroll
                for (int f = 0; f < F; ++f) {
                    const int o = (FBASE + f) * 16 + r;
                    f32x4 v;
#pragma unroll
                    for (int j = 0; j < 4; ++j) v[j] = fmaf(A[f][j], af[f], bfc[f]);
                    *(f32x4*)(ob + (size_t)o * HW) = v;
                }
            }
        }
    }

    if (STATS) {
#pragma unroll
        for (int f = 0; f < F; ++f) {
            sf[f] += __shfl_xor(sf[f], 16); sf[f] += __shfl_xor(sf[f], 32);
            qf[f] += __shfl_xor(qf[f], 16); qf[f] += __shfl_xor(qf[f], 32);
        }
        __syncthreads();               // all waves done; B region reusable
        float* S = (float*)smem;       // [F*16][8]
        float* Q = S + F * 16 * 8;
        if (lane < 16) {
#pragma unroll
            for (int f = 0; f < F; ++f) {
                S[(f * 16 + lane) * 8 + wid] = sf[f];
                Q[(f * 16 + lane) * 8 + wid] = qf[f];
            }
        }
        __syncthreads();
        for (int ch = tid; ch < F * 16; ch += 512) {
            float s = 0.f, q = 0.f;
#pragma unroll
            for (int w = 0; w < 8; ++w) { s += S[ch * 8 + w]; q += Q[ch * 8 + w]; }
            const int o = FBASE * 16 + ch;
            part[(size_t)blockIdx.x * (2 * C) + 2 * o]     = s;
            part[(size_t)blockIdx.x * (2 * C) + 2 * o + 1] = q;
        }
    }
}

__global__ __launch_bounds__(512, 2) void gemm_stats_p(
    const short* __restrict__ apack, const short* __restrict__ wbf,
    float* __restrict__ part)
{
    extern __shared__ char smem[];
    if (blockIdx.x < HBLK) gemm_body<11, 0,  true>(apack, wbf, nullptr, nullptr, part, blockIdx.x, smem);
    else                   gemm_body<10, 11, true>(apack, wbf, nullptr, nullptr, part, blockIdx.x - HBLK, smem);
}

__global__ __launch_bounds__(512, 2) void gemm_norm_p(
    const short* __restrict__ apack, const short* __restrict__ wbf,
    const float* __restrict__ ab, float* __restrict__ outp)
{
    extern __shared__ char smem[];
    if (blockIdx.x < HBLK) gemm_body<11, 0,  false>(apack, wbf, ab, outp, nullptr, blockIdx.x, smem);
    else                   gemm_body<10, 11, false>(apack, wbf, ab, outp, nullptr, blockIdx.x - HBLK, smem);
}

// ---------------------------------------------------------------- fold partials -> per-channel (a,b)
__global__ void stats_final_a(const float* __restrict__ part,
                              const float* __restrict__ gamma, const float* __restrict__ beta,
                              float* __restrict__ ab)
{
    const int o = blockIdx.x;          // 0..335
    const int lane = threadIdx.x;      // 0..63
    const int base = (o < 176) ? 0 : HBLK;
    float s = 0.f, q = 0.f;
    for (int i = lane; i < HBLK; i += 64) {
        s += part[(size_t)(base + i) * (2 * C) + 2 * o];
        q += part[(size_t)(base + i) * (2 * C) + 2 * o + 1];
    }
#pragma unroll
    for (int d = 1; d < 64; d <<= 1) { s += __shfl_xor(s, d); q += __shfl_xor(q, d); }
    if (lane == 0) {
        const float invN = 1.f / (float)(BB * HW);
        const float mean = s * invN;
        const float var  = fmaxf(q * invN - mean * mean, 0.f);
        const float rstd = rsqrtf(var + 1e-5f);
        const float a = rstd * gamma[o];
        ab[2 * o]     = a;
        ab[2 * o + 1] = beta[o] - mean * a;
    }
}

// ---------------------------------------------------------------- launch
extern "C" void kernel_launch(void* const* d_in, const int* in_sizes, int n_in,
                              void* d_out, int out_size, void* d_ws, size_t ws_size,
                              hipStream_t stream)
{
    const float* x160  = (const float*)d_in[0];
    const float* x159  = (const float*)d_in[1];
    const float* w51   = (const float*)d_in[2];
    const float* b51   = (const float*)d_in[3];
    const float* w52   = (const float*)d_in[4];
    const float* b52   = (const float*)d_in[5];
    const float* w53   = (const float*)d_in[6];
    const float* gamma = (const float*)d_in[7];
    const float* beta  = (const float*)d_in[8];
    float* out = (float*)d_out;

    // ws layout (36.4 MB)
    char* ws = (char*)d_ws;
    short* wbf   = (short*)ws;                   // 236,544 B
    float* ab    = (float*)(ws + 236544);        //   2,688 -> 239,232
    float* part  = (float*)(ws + 239232);        // 196*672*4 = 526,848 -> 766,080
    float* gate  = (float*)(ws + 766080);        // 344,064 -> 1,110,144
    short* apack = (short*)(ws + 1110144);       // 35,323,904 -> 36,434,048

    // allow >64KB dynamic LDS (attribute is persistent; call is idempotent)
    (void)hipFuncSetAttribute((const void*)gemm_stats_p,
        hipFuncAttributeMaxDynamicSharedMemorySize, BLDS);
    (void)hipFuncSetAttribute((const void*)gemm_norm_p,
        hipFuncAttributeMaxDynamicSharedMemorySize, BLDS);

    hipLaunchKernelGGL(prep_w,        dim3(231),  dim3(64),  0,    stream, w53, wbf);
    hipLaunchKernelGGL(gate_kernel,   dim3(32),   dim3(256), 0,    stream, x160, w51, b51, w52, b52, gate);
    hipLaunchKernelGGL(pack_kernel,   dim3(PBLK), dim3(128), 0,    stream, x159, gate, apack);
    hipLaunchKernelGGL(gemm_stats_p,  dim3(GBLK), dim3(512), BLDS, stream, apack, wbf, part);
    hipLaunchKernelGGL(stats_final_a, dim3(C),    dim3(64),  0,    stream, part, gamma, beta, ab);
    hipLaunchKernelGGL(gemm_norm_p,   dim3(GBLK), dim3(512), BLDS, stream, apack, wbf, ab, out);
}

// Round 8
// 167.304 us; speedup vs baseline: 2.8661x; 2.8661x over previous
//
#include <hip/hip_runtime.h>
#include <hip/hip_bf16.h>

#define C   336
#define CR  84
#define BB  256
#define HW  196           // 14*14
#define NKC 11            // K chunks of 32 (K padded to 352)
#define NNF 21            // 336/16 N fragments (real)
#define NFP 24            // padded N fragments per chunk (uniform 6 stage loads/wave)
#define BUFS (NFP*512)    // shorts per LDS B buffer
#define NBLK 784          // gemm/norm grids: 784 blocks x 4 waves/tiles
#define PBLK 1568         // pack grid
#define LDSW 344          // pack LDS row stride in shorts
#define TSTR 5632         // shorts per tile slot in apack (11*512); x166 frag blob reuses slots

typedef __attribute__((ext_vector_type(8))) short bf16x8;
typedef __attribute__((ext_vector_type(4))) float f32x4;

typedef __attribute__((address_space(3))) void       lds_vp;
typedef const __attribute__((address_space(1))) void gbl_vp;

__device__ __forceinline__ unsigned short f2bf(float f) {
    unsigned u = __builtin_bit_cast(unsigned, f);
    u += 0x7fffu + ((u >> 16) & 1u);   // round-to-nearest-even
    return (unsigned short)(u >> 16);
}

__device__ __forceinline__ float bf2f(unsigned short h) {
    unsigned u = (unsigned)h << 16;
    return __builtin_bit_cast(float, u);
}

__device__ __forceinline__ void gload_lds16(const void* g, void* l) {
    __builtin_amdgcn_global_load_lds((gbl_vp*)g, (lds_vp*)l, 16, 0, 0);
}

// ---------------------------------------------------------------- prep w53 -> bf16 frag-linear (24 frags/kc)
__global__ void prep_w(const float* __restrict__ w53, short* __restrict__ wbf) {
    const int f = blockIdx.x;           // 0..263
    const int kc = f / NFP, ff = f - kc * NFP;
    const int lane = threadIdx.x;
    const int o = ff * 16 + (lane & 15);
    const int cb = kc * 32 + (lane >> 4) * 8;
    short* dst = wbf + ((size_t)f * 64 + lane) * 8;
#pragma unroll
    for (int j = 0; j < 8; ++j) {
        const int c = cb + j;
        dst[j] = (ff < NNF && c < C) ? (short)f2bf(w53[o * C + c]) : (short)0;
    }
}

// ---------------------------------------------------------------- SE gate: LDS-staged weights, 8 batches/block
__global__ __launch_bounds__(256) void gate_kernel(
    const float* __restrict__ x160,
    const float* __restrict__ w51, const float* __restrict__ b51,
    const float* __restrict__ w52, const float* __restrict__ b52,
    float* __restrict__ gate)
{
    __shared__ float sx[8 * C];
    __shared__ float wv[8 * C];
    __shared__ float hb[8 * CR];
    const int t = threadIdx.x;
    const int b0 = blockIdx.x * 8;

    for (int i = t; i < 8 * C; i += 256) sx[i] = x160[b0 * C + i];
    __syncthreads();

    for (int o0 = 0; o0 < CR; o0 += 8) {   // layer 1
        const int nrows = (CR - o0 < 8) ? (CR - o0) : 8;
        for (int i = t; i < nrows * C; i += 256) wv[i] = w51[o0 * C + i];
        __syncthreads();
        const int pair = t >> 2, kq = t & 3;
        const int b = pair >> 3, r = pair & 7;
        float v = 0.f;
        if (r < nrows) {
            const float* wr = wv + r * C + kq * 84;
            const float* xr = sx + b * C + kq * 84;
            for (int c = 0; c < 84; ++c) v = fmaf(wr[c], xr[c], v);
        }
        v += __shfl_xor(v, 1);
        v += __shfl_xor(v, 2);
        if (kq == 0 && r < nrows)
            hb[b * CR + o0 + r] = fmaxf(v + b51[o0 + r], 0.f);
        __syncthreads();
    }

    for (int o0 = 0; o0 < C; o0 += 32) {   // layer 2
        const int nrows = (C - o0 < 32) ? (C - o0) : 32;
        for (int i = t; i < nrows * CR; i += 256) wv[i] = w52[o0 * CR + i];
        __syncthreads();
        const int b = t >> 5, r = t & 31;
        if (r < nrows) {
            const float* wr = wv + r * CR;
            const float* hr = hb + b * CR;
            float v = b52[o0 + r];
            for (int j = 0; j < CR; ++j) v = fmaf(wr[j], hr[j], v);
            gate[(b0 + b) * C + o0 + r] = 1.f / (1.f + expf(-v));
        }
        __syncthreads();
    }
}

// ---------------------------------------------------------------- pack A = bf16(x159*gate), frag-linear
__global__ __launch_bounds__(128) void pack_kernel(
    const float* __restrict__ x159, const float* __restrict__ gate,
    short* __restrict__ apack)
{
    __shared__ short at[32 * LDSW];    // 22016 B
    const int tid  = threadIdx.x;
    const int lane = tid & 63;
    const int wq   = tid >> 6;         // 0..1
    const int m0   = blockIdx.x * 32;

    {   // phase 1: 64 lanes = 32 consecutive m x 2 c (coalesced)
        const int ml = lane & 31;
        const int ch = lane >> 5;
        const int m = m0 + ml;
        const int b = m / HW;
        const int p = m - b * HW;
        const float* __restrict__ xb = x159 + (size_t)b * (C * HW) + p;
        const float* __restrict__ gb = gate + b * C;
        short* row = at + ml * LDSW;
        for (int c = wq * 2 + ch; c < C; c += 4)
            row[c] = (short)f2bf(xb[(size_t)c * HW] * gb[c]);
        const int z = 336 + (wq * 2 + ch) * 2;    // zero pad cols 336..343
        row[z] = 0; row[z + 1] = 0;
    }
    __syncthreads();

    {   // phase 2: wave wq -> tile blk*2+wq, 1KB contiguous store per kc
        const int row = lane & 15;
        const int kg  = lane >> 4;
        const short* src = at + ((wq & 1) * 16 + row) * LDSW;
        short* dst = apack + (size_t)(blockIdx.x * 2 + wq) * TSTR + lane * 8;
#pragma unroll
        for (int kc = 0; kc < NKC; ++kc) {
            const int c0 = kc * 32 + kg * 8;
            bf16x8 v = {0,0,0,0,0,0,0,0};
            if (c0 < LDSW) v = *(const bf16x8*)(src + c0);   // c0==344 -> zero frag
            *(bf16x8*)(dst + (size_t)kc * 512) = v;
        }
    }
}

// ---------------------------------------------------------------- B slice staging: exactly 6 loads per wave
__device__ __forceinline__ void stage_slice(const short* __restrict__ wbf,
                                            short* buf, int kc, int wid, int lane)
{
#pragma unroll
    for (int i = 0; i < 6; ++i) {
        const int f = i * 4 + wid;     // 4 waves x 6 = 24 frags
        gload_lds16(wbf + ((size_t)(kc * NFP + f) * 64 + lane) * 8, buf + f * 512);
    }
}

// ---------------------------------------------------------------- GEMM core (round-5 proven): counted vmcnt dbuf
__device__ __forceinline__ void gemm_core_v3(const short* __restrict__ apack,
                                             const short* __restrict__ wbf,
                                             short* bsm,
                                             int t, int lane, int wid, f32x4 acc[NNF])
{
#pragma unroll
    for (int i = 0; i < NNF; ++i) acc[i] = f32x4{0.f, 0.f, 0.f, 0.f};
    const short* ap = apack + (size_t)t * TSTR + lane * 8;

    stage_slice(wbf, bsm,        0, wid, lane);
    stage_slice(wbf, bsm + BUFS, 1, wid, lane);
    bf16x8 aa = *(const bf16x8*)ap;

#pragma unroll
    for (int kc = 0; kc < NKC; ++kc) {
        if (kc == NKC - 1) asm volatile("s_waitcnt vmcnt(0)" ::: "memory");
        else               asm volatile("s_waitcnt vmcnt(6)" ::: "memory");
        __builtin_amdgcn_s_barrier();

        bf16x8 anext = aa;
        if (kc + 1 < NKC) anext = *(const bf16x8*)(ap + (size_t)(kc + 1) * 512);

        const short* bb = bsm + (kc & 1) * BUFS + lane * 8;
#pragma unroll
        for (int nf = 0; nf < NNF; ++nf) {
            const bf16x8 bfrag = *(const bf16x8*)(bb + (size_t)nf * 512);
            acc[nf] = __builtin_amdgcn_mfma_f32_16x16x32_bf16(aa, bfrag, acc[nf], 0, 0, 0);
        }
        aa = anext;

        if (kc + 2 < NKC) {
            asm volatile("s_waitcnt lgkmcnt(0)" ::: "memory");
            __builtin_amdgcn_s_barrier();
            stage_slice(wbf, bsm + (kc & 1) * BUFS, kc + 2, wid, lane);
        }
    }
    __syncthreads();   // full drain before LDS reuse / epilogue
}

// ---------------------------------------------------------------- single GEMM pass: stats + bf16 frag-store (in place)
__global__ __launch_bounds__(256, 3) void gemm_fs(
    short* __restrict__ apack,         // read tile slot, then overwrite with x166 frags
    const short* __restrict__ wbf,
    float* __restrict__ part)
{
    __shared__ short bsm[2 * BUFS];        // 49152 B (reused as float scratch after GEMM)
    const int lane = threadIdx.x & 63;
    const int wid  = threadIdx.x >> 6;
    const int t    = blockIdx.x * 4 + wid;

    f32x4 acc[NNF];
    gemm_core_v3(apack, wbf, bsm, t, lane, wid, acc);

    // ---- store x166 as bf16, fragment-linear, over this tile's own apack slot
    unsigned short* xp = (unsigned short*)apack + (size_t)t * TSTR + lane * 4;
#pragma unroll
    for (int nf = 0; nf < NNF; ++nf) {
        uint2 d;
        d.x = (unsigned)f2bf(acc[nf][0]) | ((unsigned)f2bf(acc[nf][1]) << 16);
        d.y = (unsigned)f2bf(acc[nf][2]) | ((unsigned)f2bf(acc[nf][3]) << 16);
        *(uint2*)(xp + (size_t)nf * 256) = d;   // 64 lanes x 8B = 512B contiguous
    }

    // ---- per-block channel partials (exact f32)
    float* lds_s = (float*)bsm;            // [4][336]
    float* lds_q = lds_s + 4 * C;          // [4][336]
#pragma unroll
    for (int nf = 0; nf < NNF; ++nf) {
        float s = acc[nf][0] + acc[nf][1] + acc[nf][2] + acc[nf][3];
        float q = acc[nf][0]*acc[nf][0] + acc[nf][1]*acc[nf][1]
                + acc[nf][2]*acc[nf][2] + acc[nf][3]*acc[nf][3];
        s += __shfl_xor(s, 16); q += __shfl_xor(q, 16);
        s += __shfl_xor(s, 32); q += __shfl_xor(q, 32);
        if (lane < 16) { lds_s[wid * C + nf*16 + lane] = s; lds_q[wid * C + nf*16 + lane] = q; }
    }
    __syncthreads();
    for (int i = threadIdx.x; i < C; i += 256) {
        part[(size_t)blockIdx.x * (2*C) + 2*i]     = lds_s[i] + lds_s[C+i] + lds_s[2*C+i] + lds_s[3*C+i];
        part[(size_t)blockIdx.x * (2*C) + 2*i + 1] = lds_q[i] + lds_q[C+i] + lds_q[2*C+i] + lds_q[3*C+i];
    }
}

// ---------------------------------------------------------------- fold partials -> per-channel (a,b)
__global__ void stats_final_a(const float* __restrict__ part,
                              const float* __restrict__ gamma, const float* __restrict__ beta,
                              float* __restrict__ ab)
{
    const int o = blockIdx.x;          // 0..335
    const int lane = threadIdx.x;      // 0..63
    float s = 0.f, q = 0.f;
    for (int i = lane; i < NBLK; i += 64) {
        s += part[(size_t)i * (2*C) + 2*o];
        q += part[(size_t)i * (2*C) + 2*o + 1];
    }
#pragma unroll
    for (int d = 1; d < 64; d <<= 1) { s += __shfl_xor(s, d); q += __shfl_xor(q, d); }
    if (lane == 0) {
        const float invN = 1.f / (float)(BB * HW);
        const float mean = s * invN;
        const float var  = fmaxf(q * invN - mean * mean, 0.f);
        const float rstd = rsqrtf(var + 1e-5f);
        const float a = rstd * gamma[o];
        ab[2*o]     = a;
        ab[2*o + 1] = beta[o] - mean * a;
    }
}

// ---------------------------------------------------------------- norm + transpose: frag bf16 -> out f32
// block = 64 m-rows (4 tile slots); LDS-stage 43KB frag blob, transpose-read, coalesced f32 stores.
__global__ __launch_bounds__(256) void norm_t(
    const short* __restrict__ apack,   // x166 frag blob (tile-slot stride TSTR)
    const float* __restrict__ ab, float* __restrict__ out)
{
    __shared__ unsigned short xs[4 * NNF * 256];   // 21504 shorts = 43008 B
    __shared__ float s_ab[2 * C];
    const int tid  = threadIdx.x;
    const int lane = tid & 63;
    const int wid  = tid >> 6;
    const int T0   = blockIdx.x * 4;

    // stage: 42 wave-calls x 1KB; per-lane global src handles tile-slot stride
    const unsigned short* src = (const unsigned short*)apack;
    for (int s = wid; s < 42; s += 4) {
        const int u    = s * 64 + lane;        // 16B unit, 672 per tile
        const int tile = u / 672;
        const int win  = u - tile * 672;
        gload_lds16(src + (size_t)(T0 + tile) * TSTR + (size_t)win * 8,
                    (unsigned short*)xs + (size_t)s * 512);
    }
    for (int i = tid; i < 2 * C; i += 256) s_ab[i] = ab[i];
    __syncthreads();                           // drains vmcnt+lgkm

    // transpose-read + normalize + store
    const int o_sub = lane >> 4;               // 0..3
    const int q     = lane & 15;               // m-quad index
    const int tl    = q >> 2;
    const int qq    = q & 3;
    const int r     = wid * 4 + o_sub;         // 0..15
    const int m     = blockIdx.x * 64 + q * 4;
    const int bC    = m / HW;
    const int pC    = m - bC * HW;
    float* __restrict__ ob = out + (size_t)bC * (C * HW) + pC;

#pragma unroll
    for (int i = 0; i < NNF; ++i) {
        const int o = i * 16 + r;
        const unsigned short* pp = xs + (size_t)tl * (NNF*256) + (size_t)i * 256
                                      + (size_t)(qq * 16 + r) * 4;
        const uint2 d = *(const uint2*)pp;
        const float a  = s_ab[2*o];
        const float b2 = s_ab[2*o + 1];
        f32x4 v;
        v[0] = fmaf(bf2f((unsigned short)(d.x & 0xffff)), a, b2);
        v[1] = fmaf(bf2f((unsigned short)(d.x >> 16)),    a, b2);
        v[2] = fmaf(bf2f((unsigned short)(d.y & 0xffff)), a, b2);
        v[3] = fmaf(bf2f((unsigned short)(d.y >> 16)),    a, b2);
        *(f32x4*)(ob + (size_t)o * HW) = v;    // 4 consecutive p; 16 q-lanes -> 256B contiguous
    }
}

// ---------------------------------------------------------------- launch
extern "C" void kernel_launch(void* const* d_in, const int* in_sizes, int n_in,
                              void* d_out, int out_size, void* d_ws, size_t ws_size,
                              hipStream_t stream)
{
    const float* x160  = (const float*)d_in[0];
    const float* x159  = (const float*)d_in[1];
    const float* w51   = (const float*)d_in[2];
    const float* b51   = (const float*)d_in[3];
    const float* w52   = (const float*)d_in[4];
    const float* b52   = (const float*)d_in[5];
    const float* w53   = (const float*)d_in[6];
    const float* gamma = (const float*)d_in[7];
    const float* beta  = (const float*)d_in[8];
    float* out = (float*)d_out;

    // ws layout (37.7 MB, proven to fit; gate aliases part — dead before part is written)
    char* ws = (char*)d_ws;
    short* wbf   = (short*)ws;                   // 270,336 B
    float* ab    = (float*)(ws + 270336);        //   2,688 -> 273,024
    float* part  = (float*)(ws + 273024);        // 784*672*4 = 2,107,392 -> 2,380,416
    float* gate  = (float*)(ws + 273024);        // 344,064 B (alias over part)
    short* apack = (short*)(ws + 2380416);       // 3136*5632*2 = 35,323,904 -> 37,704,320

    hipLaunchKernelGGL(prep_w,        dim3(11*NFP), dim3(64),  0, stream, w53, wbf);
    hipLaunchKernelGGL(gate_kernel,   dim3(32),     dim3(256), 0, stream, x160, w51, b51, w52, b52, gate);
    hipLaunchKernelGGL(pack_kernel,   dim3(PBLK),   dim3(128), 0, stream, x159, gate, apack);
    hipLaunchKernelGGL(gemm_fs,       dim3(NBLK),   dim3(256), 0, stream, apack, wbf, part);
    hipLaunchKernelGGL(stats_final_a, dim3(C),      dim3(64),  0, stream, part, gamma, beta, ab);
    hipLaunchKernelGGL(norm_t,        dim3(NBLK),   dim3(256), 0, stream, apack, ab, out);
}

// Round 11
// 109.258 us; speedup vs baseline: 4.3887x; 1.5313x over previous
//
#include <hip/hip_runtime.h>
#include <hip/hip_bf16.h>

#define C   336
#define CR  84
#define BB  256
#define HW  196           // 14*14
#define NKC 11            // K chunks of 32 (K padded to 352)
#define NNF 21            // 336/16 N fragments (real)
#define NFP 24            // padded N fragments per chunk (uniform 6 stage loads/wave)
#define BUFS (NFP*512)    // shorts per LDS B buffer
#define NBLK 784          // gemm/norm grids: 784 blocks x 4 waves/tiles
#define PBLK 1568         // pack grid
#define LDSW 344          // pack LDS row stride in shorts
#define TSTR 5632         // shorts per tile slot in apack (11*512)

typedef __attribute__((ext_vector_type(8))) short bf16x8;
typedef __attribute__((ext_vector_type(4))) float f32x4;

typedef __attribute__((address_space(3))) void       lds_vp;
typedef const __attribute__((address_space(1))) void gbl_vp;

__device__ __forceinline__ unsigned short f2bf(float f) {
    unsigned u = __builtin_bit_cast(unsigned, f);
    u += 0x7fffu + ((u >> 16) & 1u);   // round-to-nearest-even
    return (unsigned short)(u >> 16);
}

__device__ __forceinline__ float bf2f(unsigned short h) {
    unsigned u = (unsigned)h << 16;
    return __builtin_bit_cast(float, u);
}

__device__ __forceinline__ void gload_lds16(const void* g, void* l) {
    __builtin_amdgcn_global_load_lds((gbl_vp*)g, (lds_vp*)l, 16, 0, 0);
}

// ---------------------------------------------------------------- prep w53 -> bf16 frag-linear (24 frags/kc)
__global__ void prep_w(const float* __restrict__ w53, short* __restrict__ wbf) {
    const int f = blockIdx.x;           // 0..263
    const int kc = f / NFP, ff = f - kc * NFP;
    const int lane = threadIdx.x;
    const int o = ff * 16 + (lane & 15);
    const int cb = kc * 32 + (lane >> 4) * 8;
    short* dst = wbf + ((size_t)f * 64 + lane) * 8;
#pragma unroll
    for (int j = 0; j < 8; ++j) {
        const int c = cb + j;
        dst[j] = (ff < NNF && c < C) ? (short)f2bf(w53[o * C + c]) : (short)0;
    }
}

// ---------------------------------------------------------------- SE gate: block per batch, 384 thr (proven r4-r6)
__global__ void gate_kernel(const float* __restrict__ x160,
                            const float* __restrict__ w51, const float* __restrict__ b51,
                            const float* __restrict__ w52, const float* __restrict__ b52,
                            float* __restrict__ gate)
{
    __shared__ float s[C];
    __shared__ float red[C];
    __shared__ float h[CR];
    const int b = blockIdx.x, t = threadIdx.x;
    if (t < C) s[t] = x160[b * C + t];
    __syncthreads();
    if (t < C) {                       // layer 1: 84 outputs x 4 threads
        const int o = t >> 2, j = t & 3;
        float a = 0.f;
        const float* wr = w51 + o * C;
        for (int c = j; c < C; c += 4) a = fmaf(wr[c], s[c], a);
        red[t] = a;
    }
    __syncthreads();
    if (t < CR) {
        float a = red[4*t] + red[4*t+1] + red[4*t+2] + red[4*t+3] + b51[t];
        h[t] = fmaxf(a, 0.f);
    }
    __syncthreads();
    if (t < C) {                       // layer 2
        float a = b52[t];
        const float* wr = w52 + t * CR;
        for (int j = 0; j < CR; ++j) a = fmaf(wr[j], h[j], a);
        gate[b * C + t] = 1.f / (1.f + expf(-a));
    }
}

// ---------------------------------------------------------------- pack A = bf16(x159*gate), frag-linear
__global__ __launch_bounds__(128) void pack_kernel(
    const float* __restrict__ x159, const float* __restrict__ gate,
    short* __restrict__ apack)
{
    __shared__ short at[32 * LDSW];    // 22016 B
    const int tid  = threadIdx.x;
    const int lane = tid & 63;
    const int wq   = tid >> 6;         // 0..1
    const int m0   = blockIdx.x * 32;

    {   // phase 1: 64 lanes = 32 consecutive m x 2 c (coalesced)
        const int ml = lane & 31;
        const int ch = lane >> 5;
        const int m = m0 + ml;
        const int b = m / HW;
        const int p = m - b * HW;
        const float* __restrict__ xb = x159 + (size_t)b * (C * HW) + p;
        const float* __restrict__ gb = gate + b * C;
        short* row = at + ml * LDSW;
        for (int c = wq * 2 + ch; c < C; c += 4)
            row[c] = (short)f2bf(xb[(size_t)c * HW] * gb[c]);
        const int z = 336 + (wq * 2 + ch) * 2;    // zero pad cols 336..343
        row[z] = 0; row[z + 1] = 0;
    }
    __syncthreads();

    {   // phase 2: wave wq -> tile blk*2+wq, 1KB contiguous store per kc
        const int row = lane & 15;
        const int kg  = lane >> 4;
        const short* src = at + ((wq & 1) * 16 + row) * LDSW;
        short* dst = apack + (size_t)(blockIdx.x * 2 + wq) * TSTR + lane * 8;
#pragma unroll
        for (int kc = 0; kc < NKC; ++kc) {
            const int c0 = kc * 32 + kg * 8;
            bf16x8 v = {0,0,0,0,0,0,0,0};
            if (c0 < LDSW) v = *(const bf16x8*)(src + c0);   // c0==344 -> zero frag
            *(bf16x8*)(dst + (size_t)kc * 512) = v;
        }
    }
}

// ---------------------------------------------------------------- B slice staging: exactly 6 loads per wave
__device__ __forceinline__ void stage_slice(const short* __restrict__ wbf,
                                            short* buf, int kc, int wid, int lane)
{
#pragma unroll
    for (int i = 0; i < 6; ++i) {
        const int f = i * 4 + wid;     // 4 waves x 6 = 24 frags
        gload_lds16(wbf + ((size_t)(kc * NFP + f) * 64 + lane) * 8, buf + f * 512);
    }
}

// ---------------------------------------------------------------- GEMM core: counted vmcnt dbuf (round-5 proven)
__device__ __forceinline__ void gemm_core_v3(const short* __restrict__ apack,
                                             const short* __restrict__ wbf,
                                             short* bsm,
                                             int t, int lane, int wid, f32x4 acc[NNF])
{
#pragma unroll
    for (int i = 0; i < NNF; ++i) acc[i] = f32x4{0.f, 0.f, 0.f, 0.f};
    const short* ap = apack + (size_t)t * TSTR + lane * 8;

    stage_slice(wbf, bsm,        0, wid, lane);
    stage_slice(wbf, bsm + BUFS, 1, wid, lane);
    bf16x8 aa = *(const bf16x8*)ap;

#pragma unroll
    for (int kc = 0; kc < NKC; ++kc) {
        if (kc == NKC - 1) asm volatile("s_waitcnt vmcnt(0)" ::: "memory");
        else               asm volatile("s_waitcnt vmcnt(6)" ::: "memory");
        __builtin_amdgcn_s_barrier();

        bf16x8 anext = aa;
        if (kc + 1 < NKC) anext = *(const bf16x8*)(ap + (size_t)(kc + 1) * 512);

        const short* bb = bsm + (kc & 1) * BUFS + lane * 8;
#pragma unroll
        for (int nf = 0; nf < NNF; ++nf) {
            const bf16x8 bfrag = *(const bf16x8*)(bb + (size_t)nf * 512);
            acc[nf] = __builtin_amdgcn_mfma_f32_16x16x32_bf16(aa, bfrag, acc[nf], 0, 0, 0);
        }
        aa = anext;

        if (kc + 2 < NKC) {
            asm volatile("s_waitcnt lgkmcnt(0)" ::: "memory");
            __builtin_amdgcn_s_barrier();
            stage_slice(wbf, bsm + (kc & 1) * BUFS, kc + 2, wid, lane);
        }
    }
    __syncthreads();   // full drain before LDS reuse / epilogue
}

// ---------------------------------------------------------------- single GEMM pass: stats + bf16 frag-store (in place)
__global__ __launch_bounds__(256, 3) void gemm_fs(
    short* __restrict__ apack,         // read tile slot, then overwrite with x166 frags
    const short* __restrict__ wbf,
    float* __restrict__ part)
{
    __shared__ short bsm[2 * BUFS];        // 49152 B (reused as float scratch after GEMM)
    const int lane = threadIdx.x & 63;
    const int wid  = threadIdx.x >> 6;
    const int t    = blockIdx.x * 4 + wid;

    f32x4 acc[NNF];
    gemm_core_v3(apack, wbf, bsm, t, lane, wid, acc);

    // ---- store x166 as bf16, fragment-linear, over this tile's own apack slot
    unsigned short* xp = (unsigned short*)apack + (size_t)t * TSTR + lane * 4;
#pragma unroll
    for (int nf = 0; nf < NNF; ++nf) {
        uint2 d;
        d.x = (unsigned)f2bf(acc[nf][0]) | ((unsigned)f2bf(acc[nf][1]) << 16);
        d.y = (unsigned)f2bf(acc[nf][2]) | ((unsigned)f2bf(acc[nf][3]) << 16);
        *(uint2*)(xp + (size_t)nf * 256) = d;   // 64 lanes x 8B = 512B contiguous
    }

    // ---- per-block channel partials (exact f32)
    float* lds_s = (float*)bsm;            // [4][336]
    float* lds_q = lds_s + 4 * C;          // [4][336]
#pragma unroll
    for (int nf = 0; nf < NNF; ++nf) {
        float s = acc[nf][0] + acc[nf][1] + acc[nf][2] + acc[nf][3];
        float q = acc[nf][0]*acc[nf][0] + acc[nf][1]*acc[nf][1]
                + acc[nf][2]*acc[nf][2] + acc[nf][3]*acc[nf][3];
        s += __shfl_xor(s, 16); q += __shfl_xor(q, 16);
        s += __shfl_xor(s, 32); q += __shfl_xor(q, 32);
        if (lane < 16) { lds_s[wid * C + nf*16 + lane] = s; lds_q[wid * C + nf*16 + lane] = q; }
    }
    __syncthreads();
    for (int i = threadIdx.x; i < C; i += 256) {
        part[(size_t)blockIdx.x * (2*C) + 2*i]     = lds_s[i] + lds_s[C+i] + lds_s[2*C+i] + lds_s[3*C+i];
        part[(size_t)blockIdx.x * (2*C) + 2*i + 1] = lds_q[i] + lds_q[C+i] + lds_q[2*C+i] + lds_q[3*C+i];
    }
}

// ---------------------------------------------------------------- fold partials -> per-channel (a,b)
__global__ void stats_final_a(const float* __restrict__ part,
                              const float* __restrict__ gamma, const float* __restrict__ beta,
                              float* __restrict__ ab)
{
    const int o = blockIdx.x;          // 0..335
    const int lane = threadIdx.x;      // 0..63
    float s = 0.f, q = 0.f;
    for (int i = lane; i < NBLK; i += 64) {
        s += part[(size_t)i * (2*C) + 2*o];
        q += part[(size_t)i * (2*C) + 2*o + 1];
    }
#pragma unroll
    for (int d = 1; d < 64; d <<= 1) { s += __shfl_xor(s, d); q += __shfl_xor(q, d); }
    if (lane == 0) {
        const float invN = 1.f / (float)(BB * HW);
        const float mean = s * invN;
        const float var  = fmaxf(q * invN - mean * mean, 0.f);
        const float rstd = rsqrtf(var + 1e-5f);
        const float a = rstd * gamma[o];
        ab[2*o]     = a;
        ab[2*o + 1] = beta[o] - mean * a;
    }
}

// ---------------------------------------------------------------- norm + transpose: frag bf16 -> out f32 (round-7 exact, HW-proven)
__global__ __launch_bounds__(256) void norm_t(
    const short* __restrict__ apack,   // x166 frag blob (tile-slot stride TSTR)
    const float* __restrict__ ab, float* __restrict__ out)
{
    __shared__ unsigned short xs[4 * NNF * 256];   // 21504 shorts = 43008 B
    __shared__ float s_ab[2 * C];
    const int tid  = threadIdx.x;
    const int lane = tid & 63;
    const int wid  = tid >> 6;
    const int T0   = blockIdx.x * 4;

    // stage: 42 wave-calls x 1KB; per-lane global src handles tile-slot stride
    const unsigned short* src = (const unsigned short*)apack;
    for (int s = wid; s < 42; s += 4) {
        const int u    = s * 64 + lane;        // 16B unit, 672 per tile
        const int tile = u / 672;
        const int win  = u - tile * 672;
        gload_lds16(src + (size_t)(T0 + tile) * TSTR + (size_t)win * 8,
                    (unsigned short*)xs + (size_t)s * 512);
    }
    for (int i = tid; i < 2 * C; i += 256) s_ab[i] = ab[i];
    __syncthreads();                           // drains vmcnt+lgkm

    // transpose-read + normalize + store
    const int o_sub = lane >> 4;               // 0..3
    const int q     = lane & 15;               // m-quad index
    const int tl    = q >> 2;
    const int qq    = q & 3;
    const int r     = wid * 4 + o_sub;         // 0..15
    const int m     = blockIdx.x * 64 + q * 4;
    const int bC    = m / HW;
    const int pC    = m - bC * HW;
    float* __restrict__ ob = out + (size_t)bC * (C * HW) + pC;

#pragma unroll
    for (int i = 0; i < NNF; ++i) {
        const int o = i * 16 + r;
        const unsigned short* pp = xs + (size_t)tl * (NNF*256) + (size_t)i * 256
                                      + (size_t)(qq * 16 + r) * 4;
        const uint2 d = *(const uint2*)pp;
        const float a  = s_ab[2*o];
        const float b2 = s_ab[2*o + 1];
        f32x4 v;
        v[0] = fmaf(bf2f((unsigned short)(d.x & 0xffff)), a, b2);
        v[1] = fmaf(bf2f((unsigned short)(d.x >> 16)),    a, b2);
        v[2] = fmaf(bf2f((unsigned short)(d.y & 0xffff)), a, b2);
        v[3] = fmaf(bf2f((unsigned short)(d.y >> 16)),    a, b2);
        *(f32x4*)(ob + (size_t)o * HW) = v;    // 16 q-lanes -> 256B contiguous
    }
}

// ---------------------------------------------------------------- launch
extern "C" void kernel_launch(void* const* d_in, const int* in_sizes, int n_in,
                              void* d_out, int out_size, void* d_ws, size_t ws_size,
                              hipStream_t stream)
{
    const float* x160  = (const float*)d_in[0];
    const float* x159  = (const float*)d_in[1];
    const float* w51   = (const float*)d_in[2];
    const float* b51   = (const float*)d_in[3];
    const float* w52   = (const float*)d_in[4];
    const float* b52   = (const float*)d_in[5];
    const float* w53   = (const float*)d_in[6];
    const float* gamma = (const float*)d_in[7];
    const float* beta  = (const float*)d_in[8];
    float* out = (float*)d_out;

    // ws layout (37.7 MB, proven to fit; gate aliases part — dead before part is written)
    char* ws = (char*)d_ws;
    short* wbf   = (short*)ws;                   // 270,336 B
    float* ab    = (float*)(ws + 270336);        //   2,688 -> 273,024
    float* part  = (float*)(ws + 273024);        // 784*672*4 = 2,107,392 -> 2,380,416
    float* gate  = (float*)(ws + 273024);        // 344,064 B (alias over part)
    short* apack = (short*)(ws + 2380416);       // 3136*5632*2 = 35,323,904 -> 37,704,320

    hipLaunchKernelGGL(prep_w,        dim3(11*NFP), dim3(64),  0, stream, w53, wbf);
    hipLaunchKernelGGL(gate_kernel,   dim3(BB),     dim3(384), 0, stream, x160, w51, b51, w52, b52, gate);
    hipLaunchKernelGGL(pack_kernel,   dim3(PBLK),   dim3(128), 0, stream, x159, gate, apack);
    hipLaunchKernelGGL(gemm_fs,       dim3(NBLK),   dim3(256), 0, stream, apack, wbf, part);
    hipLaunchKernelGGL(stats_final_a, dim3(C),      dim3(64),  0, stream, part, gamma, beta, ab);
    hipLaunchKernelGGL(norm_t,        dim3(NBLK),   dim3(256), 0, stream, apack, ab, out);
}